// Round 18
// baseline (95.276 us; speedup 1.0000x reference)
//
#include <hip/hip_runtime.h>
#include <hip/hip_fp16.h>
#include <math.h>

#define NEG 0.2f
#define LOG2E 1.4426950408889634f

typedef float f32x4 __attribute__((ext_vector_type(4)));
typedef _Float16 half8 __attribute__((ext_vector_type(8)));
typedef _Float16 h2v __attribute__((ext_vector_type(2)));
typedef short s16x2 __attribute__((ext_vector_type(2)));

#if __has_builtin(__builtin_amdgcn_exp2f)
#define EXP2F(x) __builtin_amdgcn_exp2f(x)
#else
#define EXP2F(x) exp2f(x)
#endif

__device__ inline uint cvt2(float a, float b) {
  union {
    decltype(__builtin_amdgcn_cvt_pkrtz(0.f, 0.f)) v;
    uint u;
  } x;
  x.v = __builtin_amdgcn_cvt_pkrtz(a, b);
  return x.u;
}

__device__ inline h2v u2h(uint u) {
  union {
    uint u;
    h2v v;
  } x;
  x.u = u;
  return x.v;
}

__device__ inline uint h2u(h2v v) {
  union {
    uint u;
    h2v v;
  } x;
  x.v = v;
  return x.u;
}

// bits 15/31 -> 0xFFFF/0x0000 per half (v_pk_ashrrev_i16)
__device__ inline uint sgn16(uint t) {
  union {
    uint u;
    s16x2 v;
  } x;
  x.u = t;
  x.v = x.v >> 15;
  return x.u;
}

// plane-SoA pack layout, per 256-edge group g:
//   epk32[g*8 + half*4 + p] = half `half` of ballot(e[g*256 + 4*l + p])

// ---------------- K-A: prep (W->frag + ermx zero) || pack half 1 -----------
__global__ __launch_bounds__(256, 4) void prep_pack(
    const float* __restrict__ W, ushort* __restrict__ wf, uint* __restrict__ ermx,
    const int* __restrict__ e, uint* __restrict__ epk32) {
  const int bx = blockIdx.x;
  const int t = threadIdx.x;
  const int l = t & 63;
  if (bx < 33) {
    if (bx == 32) {
      if (t < 32) ermx[t] = 0u;  // atomicMax identity under monotone key map
      return;
    }
    const int h = bx >> 2, ct = bx & 3;
#pragma unroll
    for (int s = 0; s < 2; ++s) {
      int slot = t + s * 256;  // (kk,l)
      int ll = slot & 63, kk = slot >> 6;
      int col = h * 64 + ct * 16 + (ll & 15);
      int k0 = kk * 32 + (ll >> 4) * 8;
      uint outv[4];
#pragma unroll
      for (int c = 0; c < 4; ++c) {
        float x0 = W[(size_t)(k0 + 2 * c) * 512 + col];
        float x1 = W[(size_t)(k0 + 2 * c + 1) * 512 + col];
        outv[c] = cvt2(x0, x1);
      }
      *(uint4*)&wf[(((size_t)((h * 4 + ct) * 8 + kk)) * 64 + ll) * 8] = *(uint4*)outv;
    }
    return;
  }
  // ---- pack half 1: groups [0, 32768), int4 loads ----
  const size_t g0 = (size_t)(bx - 33) * 16 + (t >> 6) * 4;
#pragma unroll
  for (int it = 0; it < 4; ++it) {
    const size_t gi = g0 + it;
    int4 v = *(const int4*)(e + gi * 256 + l * 4);
    unsigned long long b0 = __ballot(v.x != 0);
    unsigned long long b1 = __ballot(v.y != 0);
    unsigned long long b2 = __ballot(v.z != 0);
    unsigned long long b3 = __ballot(v.w != 0);
    if (l == 0) {
      uint4 lo, hi;
      lo.x = (uint)b0;
      lo.y = (uint)b1;
      lo.z = (uint)b2;
      lo.w = (uint)b3;
      hi.x = (uint)(b0 >> 32);
      hi.y = (uint)(b1 >> 32);
      hi.z = (uint)(b2 >> 32);
      hi.w = (uint)(b3 >> 32);
      *(uint4*)&epk32[gi * 8] = lo;
      *(uint4*)&epk32[gi * 8 + 4] = hi;
    }
  }
}

// ---------------- K-B: pack half 2 (2/3) || MFMA proj (1/3) ----------------
__global__ __launch_bounds__(256, 4) void pack2_proj(
    const int* __restrict__ e, uint* __restrict__ epk32,
    const float* __restrict__ A, const ushort* __restrict__ wf,
    const float* __restrict__ aw, ushort* __restrict__ mt,
    float* __restrict__ el, float* __restrict__ er, uint* __restrict__ ermx) {
  __shared__ ushort ct_lds[64][72];
  const int bx = blockIdx.x;
  const int t = threadIdx.x;
  const int l = t & 63;
  if (bx % 3 != 2) {
    // ---- pack half 2: groups [32768, 65536) ----
    const int pb = (bx / 3) * 2 + (bx % 3);
    const size_t g0 = 32768 + (size_t)pb * 16 + (t >> 6) * 4;
#pragma unroll
    for (int it = 0; it < 4; ++it) {
      const size_t gi = g0 + it;
      int4 v = *(const int4*)(e + gi * 256 + l * 4);
      unsigned long long b0 = __ballot(v.x != 0);
      unsigned long long b1 = __ballot(v.y != 0);
      unsigned long long b2 = __ballot(v.z != 0);
      unsigned long long b3 = __ballot(v.w != 0);
      if (l == 0) {
        uint4 lo, hi;
        lo.x = (uint)b0;
        lo.y = (uint)b1;
        lo.z = (uint)b2;
        lo.w = (uint)b3;
        hi.x = (uint)(b0 >> 32);
        hi.y = (uint)(b1 >> 32);
        hi.z = (uint)(b2 >> 32);
        hi.w = (uint)(b3 >> 32);
        *(uint4*)&epk32[gi * 8] = lo;
        *(uint4*)&epk32[gi * 8 + 4] = hi;
      }
    }
    return;
  }
  // ---- projection block ----
  const int pid = bx / 3;
  const int wq = t >> 6;
  const int i0 = (pid & 127) * 64;
  const int h = pid >> 7;
  const int b = i0 >> 11, n0 = i0 & 2047, bh = b * 8 + h;
  const int cl = l & 15, hi = l >> 4;
  const float* arow = A + (size_t)(i0 + wq * 16 + cl) * 256 + hi * 8;
  const int4* wfb = (const int4*)wf + (size_t)h * 32 * 64 + l;
  f32x4 acc[4];
#pragma unroll
  for (int ct = 0; ct < 4; ++ct) acc[ct] = (f32x4){0.f, 0.f, 0.f, 0.f};
#pragma unroll
  for (int kk = 0; kk < 8; ++kk) {
    float4 a0 = *(const float4*)(arow + kk * 32);
    float4 a1 = *(const float4*)(arow + kk * 32 + 4);
    union {
      uint u[4];
      half8 v;
    } af;
    af.u[0] = cvt2(a0.x, a0.y);
    af.u[1] = cvt2(a0.z, a0.w);
    af.u[2] = cvt2(a1.x, a1.y);
    af.u[3] = cvt2(a1.z, a1.w);
#pragma unroll
    for (int ct = 0; ct < 4; ++ct) {
      union {
        int4 i;
        half8 v;
      } bf;
      bf.i = wfb[((size_t)ct * 8 + kk) * 64];
      acc[ct] = __builtin_amdgcn_mfma_f32_16x16x32_f16(af.v, bf.v, acc[ct], 0, 0, 0);
    }
  }
  float alc[4], arc[4];
#pragma unroll
  for (int ct = 0; ct < 4; ++ct) {
    alc[ct] = aw[h * 128 + ct * 16 + cl];
    arc[ct] = aw[h * 128 + 64 + ct * 16 + cl];
  }
  float ermax_loc = -1e30f;
#pragma unroll
  for (int reg = 0; reg < 4; ++reg) {
    float pl = acc[0][reg] * alc[0] + acc[1][reg] * alc[1] + acc[2][reg] * alc[2] +
               acc[3][reg] * alc[3];
    float pr = acc[0][reg] * arc[0] + acc[1][reg] * arc[1] + acc[2][reg] * arc[2] +
               acc[3][reg] * arc[3];
#pragma unroll
    for (int s = 1; s < 16; s <<= 1) {
      pl += __shfl_xor(pl, s);
      pr += __shfl_xor(pr, s);
    }
    if (cl == 0) {
      int n = n0 + wq * 16 + hi * 4 + reg;
      el[(size_t)bh * 2048 + n] = pl;
      er[(size_t)bh * 2048 + n] = pr;
    }
    ermax_loc = fmaxf(ermax_loc, pr);
  }
  ermax_loc = fmaxf(ermax_loc, __shfl_xor(ermax_loc, 16));
  ermax_loc = fmaxf(ermax_loc, __shfl_xor(ermax_loc, 32));
  if (l == 0) {
    uint bits = __float_as_uint(ermax_loc);
    uint key = (bits & 0x80000000u) ? ~bits : (bits | 0x80000000u);
    atomicMax(&ermx[bh], key);
  }
#pragma unroll
  for (int ct = 0; ct < 4; ++ct) {
    ushort4 us;
    us.x = __half_as_ushort(__float2half(acc[ct][0]));
    us.y = __half_as_ushort(__float2half(acc[ct][1]));
    us.z = __half_as_ushort(__float2half(acc[ct][2]));
    us.w = __half_as_ushort(__float2half(acc[ct][3]));
    *(ushort4*)&ct_lds[ct * 16 + cl][wq * 16 + hi * 4] = us;
  }
  __syncthreads();
  {
    const int f = t >> 5, s = t & 31;
    const int g = f >> 2, nt = f & 3;
    const int r = nt * 16 + (s & 15);
    const int cm = g * 32 + (s >> 4) * 8;
    int4 v0 = *(const int4*)&ct_lds[r][cm];
    int4 v1 = *(const int4*)&ct_lds[r][cm + 16];
    const size_t base = ((size_t)bh * 32 + (n0 >> 6)) * 4096 + f * 512;
    *(int4*)&mt[base + s * 8] = v0;
    *(int4*)&mt[base + (s + 32) * 8] = v1;
  }
}

// ---------------- K-C: factorized masked softmax + PV via MFMA -------------
// 2-wave block, 64 rows (32 rows/wave = 2 MFMA row-groups), full j-range.
// Each V fragment LDS-read now feeds 2 MFMAs -> LDS traffic halved.
__global__ __launch_bounds__(128, 2) void gat_attn(
    const ushort* __restrict__ mt, const uint* __restrict__ epk32,
    const float* __restrict__ el, const float* __restrict__ er,
    const uint* __restrict__ ermx, float* __restrict__ out) {
  __shared__ __align__(16) char smem[24576];  // vt dbuf 16KB + ysh 4KB + vsh 4KB
  int4* vt4 = (int4*)smem;
  uint* ysh = (uint*)(smem + 16384);  // 1024 packed f16 pairs: Y = 2^((er-emx)L)
  uint* vsh = (uint*)(smem + 20480);  // V = 2^(0.2(er-emx)L)
  const int t = threadIdx.x;
  const int l = t & 63;
  const int wq = t >> 6;  // 0..1
  const int r16 = l & 15, hi = l >> 4;
  const int i0 = blockIdx.x * 64;
  const int h = blockIdx.y, b = blockIdx.z;
  const int bh = b * 8 + h;
  const uint ky = ermx[bh];
  const float emx = __uint_as_float((ky & 0x80000000u) ? (ky ^ 0x80000000u) : ~ky);
  {  // stage Y/V packed f16 (each thread: 16 er values)
#pragma unroll
    for (int q = 0; q < 2; ++q) {
      float4 e0 = *(const float4*)&er[(size_t)bh * 2048 + t * 16 + q * 8];
      float4 e1 = *(const float4*)&er[(size_t)bh * 2048 + t * 16 + q * 8 + 4];
      uint4 yp, vp;
      yp.x = cvt2(EXP2F((e0.x - emx) * LOG2E), EXP2F((e0.y - emx) * LOG2E));
      yp.y = cvt2(EXP2F((e0.z - emx) * LOG2E), EXP2F((e0.w - emx) * LOG2E));
      yp.z = cvt2(EXP2F((e1.x - emx) * LOG2E), EXP2F((e1.y - emx) * LOG2E));
      yp.w = cvt2(EXP2F((e1.z - emx) * LOG2E), EXP2F((e1.w - emx) * LOG2E));
      vp.x = cvt2(EXP2F((e0.x - emx) * (NEG * LOG2E)), EXP2F((e0.y - emx) * (NEG * LOG2E)));
      vp.y = cvt2(EXP2F((e0.z - emx) * (NEG * LOG2E)), EXP2F((e0.w - emx) * (NEG * LOG2E)));
      vp.z = cvt2(EXP2F((e1.x - emx) * (NEG * LOG2E)), EXP2F((e1.y - emx) * (NEG * LOG2E)));
      vp.w = cvt2(EXP2F((e1.z - emx) * (NEG * LOG2E)), EXP2F((e1.w - emx) * (NEG * LOG2E)));
      *(uint4*)&ysh[t * 8 + q * 4] = yp;
      *(uint4*)&vsh[t * 8 + q * 4] = vp;
    }
  }
  const int irow0 = i0 + wq * 32 + r16;  // row-group 0
  const int irow1 = irow0 + 16;          // row-group 1
  h2v X2a, U2a, X2b, U2b;
  {
    const float s0a = el[(size_t)bh * 2048 + irow0] + emx;
    const float m2a = fmaxf(s0a, NEG * s0a) * LOG2E;
    X2a = u2h(cvt2(EXP2F(s0a * LOG2E - m2a), EXP2F(s0a * LOG2E - m2a)));
    U2a = u2h(cvt2(EXP2F(NEG * s0a * LOG2E - m2a), EXP2F(NEG * s0a * LOG2E - m2a)));
    const float s0b = el[(size_t)bh * 2048 + irow1] + emx;
    const float m2b = fmaxf(s0b, NEG * s0b) * LOG2E;
    X2b = u2h(cvt2(EXP2F(s0b * LOG2E - m2b), EXP2F(s0b * LOG2E - m2b)));
    U2b = u2h(cvt2(EXP2F(NEG * s0b * LOG2E - m2b), EXP2F(NEG * s0b * LOG2E - m2b)));
  }
  const uint* prow0 = epk32 + (size_t)(b * 2048 + irow0) * 64;
  const uint* prow1 = prow0 + 1024;  // +16 rows
  f32x4 acc0[4], acc1[4];
  f32x4 accL0 = {0.f, 0.f, 0.f, 0.f}, accL1 = {0.f, 0.f, 0.f, 0.f};
#pragma unroll
  for (int nt = 0; nt < 4; ++nt) {
    acc0[nt] = (f32x4){0.f, 0.f, 0.f, 0.f};
    acc1[nt] = (f32x4){0.f, 0.f, 0.f, 0.f};
  }
  half8 ones;
#pragma unroll
  for (int c = 0; c < 8; ++c) ones[c] = (_Float16)1.f;

  const int4* srcbase = (const int4*)mt + (size_t)bh * 32 * 512 + t;
  uint4 epw0 = *(const uint4*)&prow0[0];
  uint4 epw1 = *(const uint4*)&prow1[0];
  {  // prologue: stage V tile 0 into buf 0 (4 int4 per thread)
    int4 p0 = srcbase[0];
    int4 p1 = srcbase[128];
    int4 p2 = srcbase[256];
    int4 p3 = srcbase[384];
    vt4[t] = p0;
    vt4[t + 128] = p1;
    vt4[t + 256] = p2;
    vt4[t + 384] = p3;
  }
  __syncthreads();
  int cur = 0;
  for (int jt = 0; jt < 32; ++jt) {
    int4 nx0, nx1, nx2, nx3;
    uint4 epwn0, epwn1;
    if (jt < 31) {  // issue next-tile loads early (hide under score VALU)
      const int4* s = srcbase + (size_t)(jt + 1) * 512;
      nx0 = s[0];
      nx1 = s[128];
      nx2 = s[256];
      nx3 = s[384];
      const int jn = jt + 1;
      const int poff = ((jn >> 2) << 3) + (((jn >> 1) & 1) << 2);
      epwn0 = *(const uint4*)&prow0[poff];
      epwn1 = *(const uint4*)&prow1[poff];
    }
    half8 af0[2], af1[2];
#pragma unroll
    for (int g = 0; g < 2; ++g) {
      const uint idx = jt * 32 + g * 16 + hi * 4;
      uint4 y4 = *(const uint4*)&ysh[idx];
      uint4 v4 = *(const uint4*)&vsh[idx];
      const uint bsh = ((jt & 1) << 4) + (g << 3) + hi * 2;
      {
        const uint p0 = epw0.x >> bsh, p1 = epw0.y >> bsh;
        const uint p2 = epw0.z >> bsh, p3 = epw0.w >> bsh;
        union {
          uint u[4];
          half8 v8;
        } fr;
        fr.u[0] = h2u(__builtin_elementwise_max(X2a * u2h(y4.x), U2a * u2h(v4.x))) &
                  sgn16(((p0 & 1u) << 15) | (p1 << 31));
        fr.u[1] = h2u(__builtin_elementwise_max(X2a * u2h(y4.y), U2a * u2h(v4.y))) &
                  sgn16(((p2 & 1u) << 15) | (p3 << 31));
        fr.u[2] = h2u(__builtin_elementwise_max(X2a * u2h(y4.z), U2a * u2h(v4.z))) &
                  sgn16((((p0 >> 1) & 1u) << 15) | ((p1 >> 1) << 31));
        fr.u[3] = h2u(__builtin_elementwise_max(X2a * u2h(y4.w), U2a * u2h(v4.w))) &
                  sgn16((((p2 >> 1) & 1u) << 15) | ((p3 >> 1) << 31));
        af0[g] = fr.v8;
      }
      {
        const uint p0 = epw1.x >> bsh, p1 = epw1.y >> bsh;
        const uint p2 = epw1.z >> bsh, p3 = epw1.w >> bsh;
        union {
          uint u[4];
          half8 v8;
        } fr;
        fr.u[0] = h2u(__builtin_elementwise_max(X2b * u2h(y4.x), U2b * u2h(v4.x))) &
                  sgn16(((p0 & 1u) << 15) | (p1 << 31));
        fr.u[1] = h2u(__builtin_elementwise_max(X2b * u2h(y4.y), U2b * u2h(v4.y))) &
                  sgn16(((p2 & 1u) << 15) | (p3 << 31));
        fr.u[2] = h2u(__builtin_elementwise_max(X2b * u2h(y4.z), U2b * u2h(v4.z))) &
                  sgn16((((p0 >> 1) & 1u) << 15) | ((p1 >> 1) << 31));
        fr.u[3] = h2u(__builtin_elementwise_max(X2b * u2h(y4.w), U2b * u2h(v4.w))) &
                  sgn16((((p2 >> 1) & 1u) << 15) | ((p3 >> 1) << 31));
        af1[g] = fr.v8;
      }
    }
    const half8* fb = (const half8*)(vt4 + cur * 512);
    __builtin_amdgcn_s_setprio(1);
#pragma unroll
    for (int g = 0; g < 2; ++g) {
      accL0 = __builtin_amdgcn_mfma_f32_16x16x32_f16(af0[g], ones, accL0, 0, 0, 0);
      accL1 = __builtin_amdgcn_mfma_f32_16x16x32_f16(af1[g], ones, accL1, 0, 0, 0);
#pragma unroll
      for (int nt = 0; nt < 4; ++nt) {
        half8 bfr = fb[(g * 4 + nt) * 64 + l];
        acc0[nt] = __builtin_amdgcn_mfma_f32_16x16x32_f16(af0[g], bfr, acc0[nt], 0, 0, 0);
        acc1[nt] = __builtin_amdgcn_mfma_f32_16x16x32_f16(af1[g], bfr, acc1[nt], 0, 0, 0);
      }
    }
    __builtin_amdgcn_s_setprio(0);
    if (jt < 31) {
      int4* d = vt4 + (cur ^ 1) * 512;
      d[t] = nx0;
      d[t + 128] = nx1;
      d[t + 256] = nx2;
      d[t + 384] = nx3;
      epw0 = epwn0;
      epw1 = epwn1;
    }
    __syncthreads();
    cur ^= 1;
  }
  // ---- epilogue: accL holds full row sums in-register; no combine ----
#pragma unroll
  for (int reg = 0; reg < 4; ++reg) {
    {
      float invL = 1.f / accL0[reg];
      int orow = i0 + wq * 32 + hi * 4 + reg;
#pragma unroll
      for (int nt = 0; nt < 4; ++nt) {
        float o = acc0[nt][reg] * invL;
        float sig = 1.f / (1.f + __expf(-o));
        out[(size_t)(b * 2048 + orow) * 512 + h * 64 + nt * 16 + r16] = sig;
      }
    }
    {
      float invL = 1.f / accL1[reg];
      int orow = i0 + wq * 32 + 16 + hi * 4 + reg;
#pragma unroll
      for (int nt = 0; nt < 4; ++nt) {
        float o = acc1[nt][reg] * invL;
        float sig = 1.f / (1.f + __expf(-o));
        out[(size_t)(b * 2048 + orow) * 512 + h * 64 + nt * 16 + r16] = sig;
      }
    }
  }
}

extern "C" void kernel_launch(void* const* d_in, const int* in_sizes, int n_in,
                              void* d_out, int out_size, void* d_ws, size_t ws_size,
                              hipStream_t stream) {
  const float* nodes = (const float*)d_in[0];
  const int* edges = (const int*)d_in[1];
  const float* pw = (const float*)d_in[2];
  const float* aw = (const float*)d_in[3];
  float* out = (float*)d_out;

  ushort* mt = (ushort*)d_ws;                          // 8,388,608 B
  float* el = (float*)((char*)d_ws + 8388608);         // 262,144 B
  float* er = (float*)((char*)d_ws + 8650752);         // 262,144 B
  uint* ermx = (uint*)((char*)d_ws + 8912896);         // 128 B
  uint* epk = (uint*)((char*)d_ws + 8913024);          // 2,097,152 B
  ushort* wf = (ushort*)((char*)d_ws + 11010176);      // 262,144 B

  prep_pack<<<2081, 256, 0, stream>>>(pw, wf, ermx, edges, epk);
  pack2_proj<<<3072, 256, 0, stream>>>(edges, epk, nodes, wf, aw, mt, el, er, ermx);
  gat_attn<<<dim3(32, 8, 4), 128, 0, stream>>>(mt, epk, el, er, ermx, out);
}

// Round 19
// 85.742 us; speedup vs baseline: 1.1112x; 1.1112x over previous
//
#include <hip/hip_runtime.h>
#include <hip/hip_fp16.h>
#include <math.h>

#define NEG 0.2f
#define LOG2E 1.4426950408889634f

typedef float f32x4 __attribute__((ext_vector_type(4)));
typedef _Float16 half8 __attribute__((ext_vector_type(8)));
typedef _Float16 h2v __attribute__((ext_vector_type(2)));
typedef short s16x2 __attribute__((ext_vector_type(2)));

#if __has_builtin(__builtin_amdgcn_exp2f)
#define EXP2F(x) __builtin_amdgcn_exp2f(x)
#else
#define EXP2F(x) exp2f(x)
#endif

__device__ inline uint cvt2(float a, float b) {
  union {
    decltype(__builtin_amdgcn_cvt_pkrtz(0.f, 0.f)) v;
    uint u;
  } x;
  x.v = __builtin_amdgcn_cvt_pkrtz(a, b);
  return x.u;
}

__device__ inline h2v u2h(uint u) {
  union {
    uint u;
    h2v v;
  } x;
  x.u = u;
  return x.v;
}

__device__ inline uint h2u(h2v v) {
  union {
    uint u;
    h2v v;
  } x;
  x.v = v;
  return x.u;
}

// bits 15/31 -> 0xFFFF/0x0000 per half (v_pk_ashrrev_i16)
__device__ inline uint sgn16(uint t) {
  union {
    uint u;
    s16x2 v;
  } x;
  x.u = t;
  x.v = x.v >> 15;
  return x.u;
}

// plane-SoA pack layout, per 256-edge group g:
//   epk32[g*8 + half*4 + p] = half `half` of ballot(e[g*256 + 4*l + p])

// ---------------- K-A: prep (W->frag + ermx zero) || pack half 1 -----------
__global__ __launch_bounds__(256, 4) void prep_pack(
    const float* __restrict__ W, ushort* __restrict__ wf, uint* __restrict__ ermx,
    const int* __restrict__ e, uint* __restrict__ epk32) {
  const int bx = blockIdx.x;
  const int t = threadIdx.x;
  const int l = t & 63;
  if (bx < 33) {
    if (bx == 32) {
      if (t < 32) ermx[t] = 0u;  // atomicMax identity under monotone key map
      return;
    }
    const int h = bx >> 2, ct = bx & 3;
#pragma unroll
    for (int s = 0; s < 2; ++s) {
      int slot = t + s * 256;  // (kk,l)
      int ll = slot & 63, kk = slot >> 6;
      int col = h * 64 + ct * 16 + (ll & 15);
      int k0 = kk * 32 + (ll >> 4) * 8;
      uint outv[4];
#pragma unroll
      for (int c = 0; c < 4; ++c) {
        float x0 = W[(size_t)(k0 + 2 * c) * 512 + col];
        float x1 = W[(size_t)(k0 + 2 * c + 1) * 512 + col];
        outv[c] = cvt2(x0, x1);
      }
      *(uint4*)&wf[(((size_t)((h * 4 + ct) * 8 + kk)) * 64 + ll) * 8] = *(uint4*)outv;
    }
    return;
  }
  // ---- pack half 1: groups [0, 32768), int4 loads ----
  const size_t g0 = (size_t)(bx - 33) * 16 + (t >> 6) * 4;
#pragma unroll
  for (int it = 0; it < 4; ++it) {
    const size_t gi = g0 + it;
    int4 v = *(const int4*)(e + gi * 256 + l * 4);
    unsigned long long b0 = __ballot(v.x != 0);
    unsigned long long b1 = __ballot(v.y != 0);
    unsigned long long b2 = __ballot(v.z != 0);
    unsigned long long b3 = __ballot(v.w != 0);
    if (l == 0) {
      uint4 lo, hi;
      lo.x = (uint)b0;
      lo.y = (uint)b1;
      lo.z = (uint)b2;
      lo.w = (uint)b3;
      hi.x = (uint)(b0 >> 32);
      hi.y = (uint)(b1 >> 32);
      hi.z = (uint)(b2 >> 32);
      hi.w = (uint)(b3 >> 32);
      *(uint4*)&epk32[gi * 8] = lo;
      *(uint4*)&epk32[gi * 8 + 4] = hi;
    }
  }
}

// ---------------- K-B: pack half 2 (2/3) || MFMA proj (1/3) ----------------
__global__ __launch_bounds__(256, 4) void pack2_proj(
    const int* __restrict__ e, uint* __restrict__ epk32,
    const float* __restrict__ A, const ushort* __restrict__ wf,
    const float* __restrict__ aw, ushort* __restrict__ mt,
    float* __restrict__ el, float* __restrict__ er, uint* __restrict__ ermx) {
  __shared__ ushort ct_lds[64][72];
  const int bx = blockIdx.x;
  const int t = threadIdx.x;
  const int l = t & 63;
  if (bx % 3 != 2) {
    // ---- pack half 2: groups [32768, 65536) ----
    const int pb = (bx / 3) * 2 + (bx % 3);
    const size_t g0 = 32768 + (size_t)pb * 16 + (t >> 6) * 4;
#pragma unroll
    for (int it = 0; it < 4; ++it) {
      const size_t gi = g0 + it;
      int4 v = *(const int4*)(e + gi * 256 + l * 4);
      unsigned long long b0 = __ballot(v.x != 0);
      unsigned long long b1 = __ballot(v.y != 0);
      unsigned long long b2 = __ballot(v.z != 0);
      unsigned long long b3 = __ballot(v.w != 0);
      if (l == 0) {
        uint4 lo, hi;
        lo.x = (uint)b0;
        lo.y = (uint)b1;
        lo.z = (uint)b2;
        lo.w = (uint)b3;
        hi.x = (uint)(b0 >> 32);
        hi.y = (uint)(b1 >> 32);
        hi.z = (uint)(b2 >> 32);
        hi.w = (uint)(b3 >> 32);
        *(uint4*)&epk32[gi * 8] = lo;
        *(uint4*)&epk32[gi * 8 + 4] = hi;
      }
    }
    return;
  }
  // ---- projection block ----
  const int pid = bx / 3;
  const int wq = t >> 6;
  const int i0 = (pid & 127) * 64;
  const int h = pid >> 7;
  const int b = i0 >> 11, n0 = i0 & 2047, bh = b * 8 + h;
  const int cl = l & 15, hi = l >> 4;
  const float* arow = A + (size_t)(i0 + wq * 16 + cl) * 256 + hi * 8;
  const int4* wfb = (const int4*)wf + (size_t)h * 32 * 64 + l;
  f32x4 acc[4];
#pragma unroll
  for (int ct = 0; ct < 4; ++ct) acc[ct] = (f32x4){0.f, 0.f, 0.f, 0.f};
#pragma unroll
  for (int kk = 0; kk < 8; ++kk) {
    float4 a0 = *(const float4*)(arow + kk * 32);
    float4 a1 = *(const float4*)(arow + kk * 32 + 4);
    union {
      uint u[4];
      half8 v;
    } af;
    af.u[0] = cvt2(a0.x, a0.y);
    af.u[1] = cvt2(a0.z, a0.w);
    af.u[2] = cvt2(a1.x, a1.y);
    af.u[3] = cvt2(a1.z, a1.w);
#pragma unroll
    for (int ct = 0; ct < 4; ++ct) {
      union {
        int4 i;
        half8 v;
      } bf;
      bf.i = wfb[((size_t)ct * 8 + kk) * 64];
      acc[ct] = __builtin_amdgcn_mfma_f32_16x16x32_f16(af.v, bf.v, acc[ct], 0, 0, 0);
    }
  }
  float alc[4], arc[4];
#pragma unroll
  for (int ct = 0; ct < 4; ++ct) {
    alc[ct] = aw[h * 128 + ct * 16 + cl];
    arc[ct] = aw[h * 128 + 64 + ct * 16 + cl];
  }
  float ermax_loc = -1e30f;
#pragma unroll
  for (int reg = 0; reg < 4; ++reg) {
    float pl = acc[0][reg] * alc[0] + acc[1][reg] * alc[1] + acc[2][reg] * alc[2] +
               acc[3][reg] * alc[3];
    float pr = acc[0][reg] * arc[0] + acc[1][reg] * arc[1] + acc[2][reg] * arc[2] +
               acc[3][reg] * arc[3];
#pragma unroll
    for (int s = 1; s < 16; s <<= 1) {
      pl += __shfl_xor(pl, s);
      pr += __shfl_xor(pr, s);
    }
    if (cl == 0) {
      int n = n0 + wq * 16 + hi * 4 + reg;
      el[(size_t)bh * 2048 + n] = pl;
      er[(size_t)bh * 2048 + n] = pr;
    }
    ermax_loc = fmaxf(ermax_loc, pr);
  }
  ermax_loc = fmaxf(ermax_loc, __shfl_xor(ermax_loc, 16));
  ermax_loc = fmaxf(ermax_loc, __shfl_xor(ermax_loc, 32));
  if (l == 0) {
    uint bits = __float_as_uint(ermax_loc);
    uint key = (bits & 0x80000000u) ? ~bits : (bits | 0x80000000u);
    atomicMax(&ermx[bh], key);
  }
#pragma unroll
  for (int ct = 0; ct < 4; ++ct) {
    ushort4 us;
    us.x = __half_as_ushort(__float2half(acc[ct][0]));
    us.y = __half_as_ushort(__float2half(acc[ct][1]));
    us.z = __half_as_ushort(__float2half(acc[ct][2]));
    us.w = __half_as_ushort(__float2half(acc[ct][3]));
    *(ushort4*)&ct_lds[ct * 16 + cl][wq * 16 + hi * 4] = us;
  }
  __syncthreads();
  {
    const int f = t >> 5, s = t & 31;
    const int g = f >> 2, nt = f & 3;
    const int r = nt * 16 + (s & 15);
    const int cm = g * 32 + (s >> 4) * 8;
    int4 v0 = *(const int4*)&ct_lds[r][cm];
    int4 v1 = *(const int4*)&ct_lds[r][cm + 16];
    const size_t base = ((size_t)bh * 32 + (n0 >> 6)) * 4096 + f * 512;
    *(int4*)&mt[base + s * 8] = v0;
    *(int4*)&mt[base + (s + 32) * 8] = v1;
  }
}

// ---------------- K-C: factorized masked softmax + PV via MFMA -------------
// 4-wave block, 64 rows x full j-range, no cross-half combine.
// P_ij = max(X_i*Y_j, U_i*V_j), all factors <= 1: exp-free inner loop.
// Bijective XCD swizzle: each XCD's L2 holds 4 bh mt-slices (1 MB) + one batch's epk.
__global__ __launch_bounds__(256, 4) void gat_attn(
    const ushort* __restrict__ mt, const uint* __restrict__ epk32,
    const float* __restrict__ el, const float* __restrict__ er,
    const uint* __restrict__ ermx, float* __restrict__ out) {
  __shared__ __align__(16) char smem[24576];  // vt dbuf 16KB + ysh 4KB + vsh 4KB
  int4* vt4 = (int4*)smem;
  uint* ysh = (uint*)(smem + 16384);  // 1024 packed f16 pairs: Y = 2^((er-emx)L)
  uint* vsh = (uint*)(smem + 20480);  // V = 2^(0.2(er-emx)L)
  const int t = threadIdx.x;
  const int l = t & 63;
  const int wq = t >> 6;
  const int r16 = l & 15, hi = l >> 4;
  // bijective XCD swizzle over 1024 blocks (8 XCD x 128)
  const int bid = blockIdx.x;
  const int nb = (bid & 7) * 128 + (bid >> 3);
  const int i0 = (nb & 31) * 64;
  const int h = (nb >> 5) & 7;
  const int b = nb >> 8;
  const int bh = b * 8 + h;
  const uint ky = ermx[bh];
  const float emx = __uint_as_float((ky & 0x80000000u) ? (ky ^ 0x80000000u) : ~ky);
  {  // stage Y/V packed f16 (each thread: 8 er values)
    float4 e0 = *(const float4*)&er[(size_t)bh * 2048 + t * 8];
    float4 e1 = *(const float4*)&er[(size_t)bh * 2048 + t * 8 + 4];
    uint4 yp, vp;
    yp.x = cvt2(EXP2F((e0.x - emx) * LOG2E), EXP2F((e0.y - emx) * LOG2E));
    yp.y = cvt2(EXP2F((e0.z - emx) * LOG2E), EXP2F((e0.w - emx) * LOG2E));
    yp.z = cvt2(EXP2F((e1.x - emx) * LOG2E), EXP2F((e1.y - emx) * LOG2E));
    yp.w = cvt2(EXP2F((e1.z - emx) * LOG2E), EXP2F((e1.w - emx) * LOG2E));
    vp.x = cvt2(EXP2F((e0.x - emx) * (NEG * LOG2E)), EXP2F((e0.y - emx) * (NEG * LOG2E)));
    vp.y = cvt2(EXP2F((e0.z - emx) * (NEG * LOG2E)), EXP2F((e0.w - emx) * (NEG * LOG2E)));
    vp.z = cvt2(EXP2F((e1.x - emx) * (NEG * LOG2E)), EXP2F((e1.y - emx) * (NEG * LOG2E)));
    vp.w = cvt2(EXP2F((e1.z - emx) * (NEG * LOG2E)), EXP2F((e1.w - emx) * (NEG * LOG2E)));
    *(uint4*)&ysh[t * 4] = yp;
    *(uint4*)&vsh[t * 4] = vp;
  }
  const int irow = i0 + wq * 16 + r16;
  h2v X2, U2;
  {
    const float s0 = el[(size_t)bh * 2048 + irow] + emx;
    const float m2 = fmaxf(s0, NEG * s0) * LOG2E;   // row-max bound, log2 domain
    const float Xf = EXP2F(s0 * LOG2E - m2);        // <= 1
    const float Uf = EXP2F(NEG * s0 * LOG2E - m2);  // <= 1
    X2 = u2h(cvt2(Xf, Xf));
    U2 = u2h(cvt2(Uf, Uf));
  }
  // this row's plane words: 8 groups x 8 u32
  const uint* prow = epk32 + (size_t)(b * 2048 + irow) * 64;
  f32x4 acc[4];
  f32x4 accL = {0.f, 0.f, 0.f, 0.f};
#pragma unroll
  for (int nt = 0; nt < 4; ++nt) acc[nt] = (f32x4){0.f, 0.f, 0.f, 0.f};
  half8 ones;
#pragma unroll
  for (int c = 0; c < 8; ++c) ones[c] = (_Float16)1.f;

  const int4* srcbase = (const int4*)mt + (size_t)bh * 32 * 512 + wq * 128 + l;
  uint4 epw = *(const uint4*)&prow[0];
  {  // prologue: stage V tile 0 into buf 0
    int4 p0 = srcbase[0];
    int4 p1 = srcbase[64];
    int4* d = vt4 + wq * 128 + l;
    d[0] = p0;
    d[64] = p1;
  }
  __syncthreads();
  int cur = 0;
  for (int jt = 0; jt < 32; ++jt) {
    int4 nx0, nx1;
    uint4 epwn;
    if (jt < 31) {  // issue next-tile loads early (hide under score VALU)
      const int4* s = srcbase + (size_t)(jt + 1) * 512;
      nx0 = s[0];
      nx1 = s[64];
      const int jn = jt + 1;
      epwn = *(const uint4*)&prow[((jn >> 2) << 3) + (((jn >> 1) & 1) << 2)];
    }
    half8 af[2];
#pragma unroll
    for (int g = 0; g < 2; ++g) {
      const uint idx = jt * 32 + g * 16 + hi * 4;
      uint4 y4 = *(const uint4*)&ysh[idx];
      uint4 v4 = *(const uint4*)&vsh[idx];
      const uint bsh = ((jt & 1) << 4) + (g << 3) + hi * 2;
      const uint p0 = epw.x >> bsh, p1 = epw.y >> bsh;
      const uint p2 = epw.z >> bsh, p3 = epw.w >> bsh;
      union {
        uint u[4];
        half8 v8;
      } fr;
      fr.u[0] = h2u(__builtin_elementwise_max(X2 * u2h(y4.x), U2 * u2h(v4.x))) &
                sgn16(((p0 & 1u) << 15) | (p1 << 31));
      fr.u[1] = h2u(__builtin_elementwise_max(X2 * u2h(y4.y), U2 * u2h(v4.y))) &
                sgn16(((p2 & 1u) << 15) | (p3 << 31));
      fr.u[2] = h2u(__builtin_elementwise_max(X2 * u2h(y4.z), U2 * u2h(v4.z))) &
                sgn16((((p0 >> 1) & 1u) << 15) | ((p1 >> 1) << 31));
      fr.u[3] = h2u(__builtin_elementwise_max(X2 * u2h(y4.w), U2 * u2h(v4.w))) &
                sgn16((((p2 >> 1) & 1u) << 15) | ((p3 >> 1) << 31));
      af[g] = fr.v8;
    }
    const half8* fb = (const half8*)(vt4 + cur * 512);
    __builtin_amdgcn_s_setprio(1);
#pragma unroll
    for (int g = 0; g < 2; ++g) {
      accL = __builtin_amdgcn_mfma_f32_16x16x32_f16(af[g], ones, accL, 0, 0, 0);
#pragma unroll
      for (int nt = 0; nt < 4; ++nt) {
        half8 bfr = fb[(g * 4 + nt) * 64 + l];
        acc[nt] = __builtin_amdgcn_mfma_f32_16x16x32_f16(af[g], bfr, acc[nt], 0, 0, 0);
      }
    }
    __builtin_amdgcn_s_setprio(0);
    if (jt < 31) {
      int4* d = vt4 + (cur ^ 1) * 512 + wq * 128 + l;
      d[0] = nx0;
      d[64] = nx1;
      epw = epwn;
    }
    __syncthreads();
    cur ^= 1;
  }
  // ---- epilogue: accL holds full row sums in-register; no combine ----
#pragma unroll
  for (int reg = 0; reg < 4; ++reg) {
    float invL = 1.f / accL[reg];
    int orow = i0 + wq * 16 + hi * 4 + reg;
#pragma unroll
    for (int nt = 0; nt < 4; ++nt) {
      float o = acc[nt][reg] * invL;
      float sig = 1.f / (1.f + __expf(-o));
      out[(size_t)(b * 2048 + orow) * 512 + h * 64 + nt * 16 + r16] = sig;
    }
  }
}

extern "C" void kernel_launch(void* const* d_in, const int* in_sizes, int n_in,
                              void* d_out, int out_size, void* d_ws, size_t ws_size,
                              hipStream_t stream) {
  const float* nodes = (const float*)d_in[0];
  const int* edges = (const int*)d_in[1];
  const float* pw = (const float*)d_in[2];
  const float* aw = (const float*)d_in[3];
  float* out = (float*)d_out;

  ushort* mt = (ushort*)d_ws;                          // 8,388,608 B
  float* el = (float*)((char*)d_ws + 8388608);         // 262,144 B
  float* er = (float*)((char*)d_ws + 8650752);         // 262,144 B
  uint* ermx = (uint*)((char*)d_ws + 8912896);         // 128 B
  uint* epk = (uint*)((char*)d_ws + 8913024);          // 2,097,152 B
  ushort* wf = (ushort*)((char*)d_ws + 11010176);      // 262,144 B

  prep_pack<<<2081, 256, 0, stream>>>(pw, wf, ermx, edges, epk);
  pack2_proj<<<3072, 256, 0, stream>>>(edges, epk, nodes, wf, aw, mt, el, er, ermx);
  gat_attn<<<1024, 256, 0, stream>>>(mt, epk, el, er, ermx, out);
}